// Round 11
// baseline (355.473 us; speedup 1.0000x reference)
//
#include <hip/hip_runtime.h>
#include <hip/hip_bf16.h>

#define NN 10000
#define NE 160000
#define TILE 32
#define TPB 4     // tiles per block (pipelined)
#define A1S 296   // ushort stride for 288-col staging tile
#define A2S 136   // ushort stride for 128-col tiles

typedef __attribute__((ext_vector_type(8))) short short8;
typedef __attribute__((ext_vector_type(4))) float f32x4;

__device__ __forceinline__ float silu_f(float x) { return x / (1.0f + __expf(-x)); }
__device__ __forceinline__ unsigned short bf16u(float v) {
    __hip_bfloat16 b = __float2bfloat16(v);
    return *reinterpret_cast<unsigned short*>(&b);
}
__device__ __forceinline__ short8 pack8(float4 a, float4 b) {
    short8 r;
    r[0]=(short)bf16u(a.x); r[1]=(short)bf16u(a.y); r[2]=(short)bf16u(a.z); r[3]=(short)bf16u(a.w);
    r[4]=(short)bf16u(b.x); r[5]=(short)bf16u(b.y); r[6]=(short)bf16u(b.z); r[7]=(short)bf16u(b.w);
    return r;
}
// LDS-only barrier: orders DS ops across waves WITHOUT draining vmcnt (global loads/atomics stay in flight).
__device__ __forceinline__ void lds_barrier() {
    asm volatile("s_waitcnt lgkmcnt(0)" ::: "memory");
    __builtin_amdgcn_s_barrier();
    asm volatile("" ::: "memory");
}

// packed-weight ushort offsets
#define OFF_W1  0
#define OFF_W2  36864
#define OFF_W3  53248
#define OFF_WSC 118784
#define OFF_WU0 135168
#define OFF_WU1 151552
#define OFF_WO0 167936
#define OFF_WO1 200704
#define WP_TOTAL 233472

// ---------------- Kernel 0: pack weights (+ fused degree histogram) ----------------
__global__ __launch_bounds__(256) void convert_weights(
    const float* __restrict__ W1, const float* __restrict__ W2,
    const float* __restrict__ W3, const float* __restrict__ Wsc,
    const float* __restrict__ Wu0, const float* __restrict__ Wu1,
    const float* __restrict__ Wo0, const float* __restrict__ Wo1,
    unsigned short* __restrict__ wp,
    const int* __restrict__ edge_index, int* __restrict__ deg)
{
    int idx = blockIdx.x * 256 + threadIdx.x;
    if (idx < NE) atomicAdd(&deg[edge_index[NE + idx]], 1);
    if (idx >= WP_TOTAL) return;
    const float* src; int off, N, K;
    if      (idx < OFF_W2)  { src = W1;  off = OFF_W1;  N = 128; K = 265; }
    else if (idx < OFF_W3)  { src = W2;  off = OFF_W2;  N = 128; K = 128; }
    else if (idx < OFF_WSC) { src = W3;  off = OFF_W3;  N = 512; K = 128; }
    else if (idx < OFF_WU0) { src = Wsc; off = OFF_WSC; N = 128; K = 128; }
    else if (idx < OFF_WU1) { src = Wu0; off = OFF_WU0; N = 128; K = 128; }
    else if (idx < OFF_WO0) { src = Wu1; off = OFF_WU1; N = 128; K = 128; }
    else if (idx < OFF_WO1) { src = Wo0; off = OFF_WO0; N = 128; K = 256; }
    else                    { src = Wo1; off = OFF_WO1; N = 128; K = 256; }
    int j = idx - off;
    int kt = j / (N * 32);
    int rem = j % (N * 32);
    int n = rem >> 5, kk = rem & 31;
    int k = kt * 32 + kk;
    wp[idx] = (k < K) ? bf16u(src[k * N + n]) : (unsigned short)0;
}

// ---------------- Kernel 1: node transform (MFMA) + fused agg zeroing ----------------
__global__ __launch_bounds__(256) void node_transform(
    const float* __restrict__ node_feats,
    const unsigned short* __restrict__ wp,
    unsigned short* __restrict__ scalars_bf,
    unsigned short* __restrict__ hall,
    float* __restrict__ agg0, float* __restrict__ agg1t)
{
    __shared__ unsigned short xls[4 * 16 * 136];
    const int t = threadIdx.x;
    const int bn = blockIdx.x * 16;

    // zero this block's agg slices (independent stores; overlap with compute)
    {
        const float4 z = make_float4(0.f, 0.f, 0.f, 0.f);
        float4* a0 = (float4*)(agg0 + (size_t)bn * 256);
        #pragma unroll
        for (int i = 0; i < 4; ++i) a0[t + 256 * i] = z;
        #pragma unroll
        for (int c = 0; c < 3; ++c) {
            float4* a1 = (float4*)(agg1t + (size_t)c * NN * 256 + (size_t)bn * 256);
            #pragma unroll
            for (int i = 0; i < 4; ++i) a1[t + 256 * i] = z;
        }
    }

    for (int i = t; i < 16 * 512; i += 256) {
        int n = i >> 9, j = i & 511;
        unsigned short u = bf16u(node_feats[(size_t)(bn + n) * 512 + j]);
        if (j < 128) xls[n * 136 + j] = u;
        else {
            int jj = j - 128;
            int m = jj / 3;
            int c = jj - 3 * m;
            xls[(1 + c) * 2176 + n * 136 + m] = u;
        }
    }
    __syncthreads();

    const int wv = t >> 6, lane = t & 63, l16 = lane & 15, l4 = lane >> 4;
    const unsigned short* Wscp = wp + OFF_WSC;
    const unsigned short* Wu0p = wp + OFF_WU0;
    const unsigned short* Wu1p = wp + OFF_WU1;

    f32x4 asc[2] = {}, ah0[2] = {}, ah1[3][2] = {};
    for (int kt = 0; kt < 4; ++kt) {
        short8 ax0 = *(const short8*)(xls + l16 * 136 + kt * 32 + l4 * 8);
        short8 ax1[3];
        #pragma unroll
        for (int c = 0; c < 3; ++c)
            ax1[c] = *(const short8*)(xls + (1 + c) * 2176 + l16 * 136 + kt * 32 + l4 * 8);
        #pragma unroll
        for (int n = 0; n < 2; ++n) {
            int col = wv * 32 + n * 16 + l16;
            short8 bsc = *(const short8*)(Wscp + ((size_t)kt * 128 + col) * 32 + l4 * 8);
            short8 bu0 = *(const short8*)(Wu0p + ((size_t)kt * 128 + col) * 32 + l4 * 8);
            short8 bu1 = *(const short8*)(Wu1p + ((size_t)kt * 128 + col) * 32 + l4 * 8);
            asc[n] = __builtin_amdgcn_mfma_f32_16x16x32_bf16(ax0, bsc, asc[n], 0, 0, 0);
            ah0[n] = __builtin_amdgcn_mfma_f32_16x16x32_bf16(ax0, bu0, ah0[n], 0, 0, 0);
            #pragma unroll
            for (int c = 0; c < 3; ++c)
                ah1[c][n] = __builtin_amdgcn_mfma_f32_16x16x32_bf16(ax1[c], bu1, ah1[c][n], 0, 0, 0);
        }
    }
    const float inv = 0.08838834764831845f; // 1/sqrt(128)
    #pragma unroll
    for (int n = 0; n < 2; ++n) {
        int col = wv * 32 + n * 16 + l16;
        #pragma unroll
        for (int r = 0; r < 4; ++r) {
            int node = bn + l4 * 4 + r;
            scalars_bf[(size_t)node * 128 + col] = bf16u(asc[n][r] * inv);
            unsigned int lo = (unsigned int)bf16u(ah0[n][r] * inv)
                            | ((unsigned int)bf16u(ah1[0][n][r] * inv) << 16);
            unsigned int hi = (unsigned int)bf16u(ah1[1][n][r] * inv)
                            | ((unsigned int)bf16u(ah1[2][n][r] * inv) << 16);
            *(uint2*)(hall + ((size_t)node * 128 + col) * 4) = make_uint2(lo, hi);
        }
    }
}

// ---------------- CSR build ----------------
__global__ __launch_bounds__(1024) void scan_kernel(const int* __restrict__ deg,
                                                    int* __restrict__ cursor) {
    __shared__ int s[1024];
    const int t = threadIdx.x;
    const int base = t * 10;
    int ld[10];
    int lsum = 0;
    #pragma unroll
    for (int i = 0; i < 10; ++i) {
        int idx = base + i;
        ld[i] = (idx < NN) ? deg[idx] : 0;
        lsum += ld[i];
    }
    s[t] = lsum;
    __syncthreads();
    for (int off = 1; off < 1024; off <<= 1) {
        int u = (t >= off) ? s[t - off] : 0;
        __syncthreads();
        s[t] += u;
        __syncthreads();
    }
    int run = s[t] - lsum;
    #pragma unroll
    for (int i = 0; i < 10; ++i) {
        int idx = base + i;
        if (idx < NN) cursor[idx] = run;
        run += ld[i];
    }
}

__global__ __launch_bounds__(256) void perm_kernel(const int* __restrict__ edge_index,
                                                   int* __restrict__ cursor,
                                                   int* __restrict__ perm) {
    int e = blockIdx.x * 256 + threadIdx.x;
    if (e < NE) {
        int r = edge_index[NE + e];
        int pos = atomicAdd(&cursor[r], 1);
        perm[pos] = e;
    }
}

// ---------------- Kernel 2: pipelined MFMA edge MLP + TP + run-merged scatter ----------------
// Each block processes TPB consecutive 32-edge tiles. Tile j's compute hides tile j+1's
// header + staging HBM gathers (register-held). Barriers are LDS-only (no vmcnt drain).
__global__ __launch_bounds__(256, 5) void edge_kernel(
    const unsigned short* __restrict__ scalars_bf,
    const unsigned short* __restrict__ hall,
    const float* __restrict__ edge_attrs,
    const float* __restrict__ edge_feats,
    const float* __restrict__ lengths,
    const int* __restrict__ edge_index,
    const int* __restrict__ perm,
    const float* __restrict__ b1, const float* __restrict__ b2,
    const unsigned short* __restrict__ wp,
    float* __restrict__ agg0, float* __restrict__ agg1t)
{
    // LDS: A1 [0,18944) stride A1S; A2 [18944,27648) stride A2S;
    // A3 = A1 region stride A2S -> [0,8704); PKh fp32 [32][132] at [8704,25600).
    __shared__ unsigned char smem_u[27648];
    __shared__ int   eid_s[2][TILE];
    __shared__ int   s_s[2][TILE];
    __shared__ int   r_s[2][TILE];
    __shared__ float4 y_s[2][TILE];

    unsigned short* A1 = (unsigned short*)smem_u;
    unsigned short* A2 = (unsigned short*)(smem_u + 18944);
    unsigned short* A3 = A1;
    float* PKh = (float*)(smem_u + 8704);

    const int t = threadIdx.x;
    const int wv = t >> 6;
    const int lane = t & 63;
    const int l16 = lane & 15;
    const int l4 = lane >> 4;
    const int q = t >> 6, o = t & 63;    // scatter: wave q -> rows [q*8,q*8+8), col o
    const int rlo = q * 8;
    const int es = t >> 3, j8 = t & 7;   // staging: 8 threads per edge

    const int tile0 = blockIdx.x * TPB;

    const unsigned short* Wp1 = wp + OFF_W1;
    const unsigned short* Wp2 = wp + OFF_W2;
    const unsigned short* Wp3 = wp + OFF_W3;
    const float rs3 = 0.57735026918962576f;

    // header regs (t<32) and staged regs (all threads)
    int h_eid = 0, h_s = 0, h_r = 0; float4 h_y = make_float4(0,0,0,0);
    uint4 sv0, sv1, rv0, rv1; float efreg; float lenreg;

    // ---- prologue: header(T0) -> LDS buf0, then stage_load(T0) -> regs ----
    if (t < TILE) {
        int eid = perm[tile0 * TILE + t];
        eid_s[0][t] = eid;
        s_s[0][t] = edge_index[eid];
        r_s[0][t] = edge_index[NE + eid];
        y_s[0][t] = *(const float4*)(edge_attrs + (size_t)eid * 4);
    }
    lds_barrier();
    {
        const unsigned short* srow = scalars_bf + (size_t)s_s[0][es] * 128;
        const unsigned short* rrow = scalars_bf + (size_t)r_s[0][es] * 128;
        sv0 = *(const uint4*)(srow + j8*16);
        sv1 = *(const uint4*)(srow + j8*16 + 8);
        rv0 = *(const uint4*)(rrow + j8*16);
        rv1 = *(const uint4*)(rrow + j8*16 + 8);
        efreg = edge_feats[(size_t)eid_s[0][es] * 8 + j8];
        lenreg = (t < TILE) ? lengths[eid_s[0][t]] : 0.f;
    }

    #pragma unroll 1
    for (int j = 0; j < TPB; ++j) {
        const int cur = j & 1, nxt = cur ^ 1;

        // ---- ds_write staged regs -> A1 (+ ef/len + zero tail) ----
        *(uint4*)(A1 + es*A1S + j8*16)       = sv0;
        *(uint4*)(A1 + es*A1S + j8*16 + 8)   = sv1;
        *(uint4*)(A1 + es*A1S + 128 + j8*16)     = rv0;
        *(uint4*)(A1 + es*A1S + 128 + j8*16 + 8) = rv1;
        A1[es*A1S + 256 + j8] = bf16u(efreg);
        if (t < TILE) A1[t*A1S + 264] = bf16u(lenreg);
        for (int i = t; i < TILE * 23; i += 256) {
            int row = i / 23, c = 265 + (i - row * 23);
            A1[row*A1S + c] = 0;
        }

        // ---- pf gathers (half 0) for THIS tile ----
        uint2 pfA[8], pfB[8];
        #pragma unroll
        for (int i = 0; i < 8; ++i)
            pfA[i] = *(const uint2*)(hall + ((size_t)s_s[cur][rlo + i] * 128 + o) * 4);

        // ---- issue header loads for tile j+1 (regs; consumed after L1) ----
        if (j + 1 < TPB && t < TILE) {
            h_eid = perm[(tile0 + j + 1) * TILE + t];
            h_s = edge_index[h_eid];
            h_r = edge_index[NE + h_eid];
            h_y = *(const float4*)(edge_attrs + (size_t)h_eid * 4);
        }

        lds_barrier();   // [B1] A1 ready (vmcnt NOT drained)

        // ---- layer 1: (32 x 288) @ (288 x 128) ----
        {
            f32x4 acc[2][2] = {};
            for (int kt = 0; kt < 9; ++kt) {
                short8 a0 = *(const short8*)(A1 + (     l16)*A1S + kt*32 + l4*8);
                short8 a1 = *(const short8*)(A1 + (16 + l16)*A1S + kt*32 + l4*8);
                #pragma unroll
                for (int n = 0; n < 2; ++n) {
                    int col = (2*wv + n)*16 + l16;
                    short8 b = *(const short8*)(Wp1 + ((size_t)kt*128 + col)*32 + l4*8);
                    acc[0][n] = __builtin_amdgcn_mfma_f32_16x16x32_bf16(a0, b, acc[0][n], 0, 0, 0);
                    acc[1][n] = __builtin_amdgcn_mfma_f32_16x16x32_bf16(a1, b, acc[1][n], 0, 0, 0);
                }
            }
            #pragma unroll
            for (int n = 0; n < 2; ++n) {
                int col = (2*wv + n)*16 + l16;
                float bb = b1[col];
                #pragma unroll
                for (int m = 0; m < 2; ++m)
                    #pragma unroll
                    for (int r = 0; r < 4; ++r) {
                        int row = m*16 + l4*4 + r;
                        A2[row*A2S + col] = bf16u(silu_f(acc[m][n][r] + bb));
                    }
            }
        }
        // write header(j+1) to LDS buf nxt (hdr loads issued ~L1 ago)
        if (j + 1 < TPB && t < TILE) {
            eid_s[nxt][t] = h_eid; s_s[nxt][t] = h_s; r_s[nxt][t] = h_r; y_s[nxt][t] = h_y;
        }
        lds_barrier();   // [B2] A2 + header[nxt] ready

        // ---- issue stage_load(j+1): HBM gathers -> regs, hidden under L2+L3 ----
        if (j + 1 < TPB) {
            const unsigned short* srow = scalars_bf + (size_t)s_s[nxt][es] * 128;
            const unsigned short* rrow = scalars_bf + (size_t)r_s[nxt][es] * 128;
            sv0 = *(const uint4*)(srow + j8*16);
            sv1 = *(const uint4*)(srow + j8*16 + 8);
            rv0 = *(const uint4*)(rrow + j8*16);
            rv1 = *(const uint4*)(rrow + j8*16 + 8);
            efreg = edge_feats[(size_t)eid_s[nxt][es] * 8 + j8];
            lenreg = (t < TILE) ? lengths[eid_s[nxt][t]] : 0.f;
        }

        // ---- layer 2: (32 x 128) @ (128 x 128) -> A3 ----
        {
            f32x4 acc[2][2] = {};
            for (int kt = 0; kt < 4; ++kt) {
                short8 a0 = *(const short8*)(A2 + (     l16)*A2S + kt*32 + l4*8);
                short8 a1 = *(const short8*)(A2 + (16 + l16)*A2S + kt*32 + l4*8);
                #pragma unroll
                for (int n = 0; n < 2; ++n) {
                    int col = (2*wv + n)*16 + l16;
                    short8 b = *(const short8*)(Wp2 + ((size_t)kt*128 + col)*32 + l4*8);
                    acc[0][n] = __builtin_amdgcn_mfma_f32_16x16x32_bf16(a0, b, acc[0][n], 0, 0, 0);
                    acc[1][n] = __builtin_amdgcn_mfma_f32_16x16x32_bf16(a1, b, acc[1][n], 0, 0, 0);
                }
            }
            #pragma unroll
            for (int n = 0; n < 2; ++n) {
                int col = (2*wv + n)*16 + l16;
                float bb = b2[col];
                #pragma unroll
                for (int m = 0; m < 2; ++m)
                    #pragma unroll
                    for (int r = 0; r < 4; ++r) {
                        int row = m*16 + l4*4 + r;
                        A3[row*A2S + col] = bf16u(silu_f(acc[m][n][r] + bb));
                    }
            }
        }
        lds_barrier();   // [B3] A3 ready; PKh region (dead A1-tail/A2) usable

        // ---- layer 3: 4 segments {pass, half}; LDS-only barriers; scatter ----
        auto do_seg = [&](const int pass, const int hh, const uint2* pf) {
            const int base0 = pass ? 128 : 0;
            const int base1 = pass ? 384 : 256;
            f32x4 acc[2][2] = {};   // [fam][m]
            for (int kt = 0; kt < 4; ++kt) {
                short8 a0 = *(const short8*)(A3 + (     l16)*A2S + kt*32 + l4*8);
                short8 a1 = *(const short8*)(A3 + (16 + l16)*A2S + kt*32 + l4*8);
                #pragma unroll
                for (int fam = 0; fam < 2; ++fam) {
                    int col = (fam ? base1 : base0) + hh*64 + wv*16 + l16;
                    short8 b = *(const short8*)(Wp3 + ((size_t)kt*512 + col)*32 + l4*8);
                    acc[fam][0] = __builtin_amdgcn_mfma_f32_16x16x32_bf16(a0, b, acc[fam][0], 0, 0, 0);
                    acc[fam][1] = __builtin_amdgcn_mfma_f32_16x16x32_bf16(a1, b, acc[fam][1], 0, 0, 0);
                }
            }
            #pragma unroll
            for (int fam = 0; fam < 2; ++fam)
                #pragma unroll
                for (int m = 0; m < 2; ++m)
                    #pragma unroll
                    for (int r = 0; r < 4; ++r) {
                        int row = m*16 + l4*4 + r;
                        float y0 = y_s[cur][row].x;
                        float fold = (fam == 0) ? (pass ? rs3 : y0) : (pass ? y0 : 1.0f);
                        PKh[row*132 + fam*64 + wv*16 + l16] = acc[fam][m][r] * fold;
                    }
            lds_barrier();   // PKh visible; atomics/stores stay in flight

            {
                const int ocol = hh*64 + o;
                float ac0 = 0.f, ac1 = 0.f, ac2 = 0.f, ac3 = 0.f;
                int run_start = rlo;
                int prev_rn = r_s[cur][rlo];

                auto flush = [&](int rn, bool interior) {
                    size_t b0 = (size_t)rn * 256 + base0 + ocol;
                    if (interior) {
                        agg0[b0] = ac0;
                        agg1t[0*(size_t)NN*256 + b0] = ac1;
                        agg1t[1*(size_t)NN*256 + b0] = ac2;
                        agg1t[2*(size_t)NN*256 + b0] = ac3;
                    } else {
                        atomicAdd(agg0 + b0, ac0);
                        atomicAdd(agg1t + 0*(size_t)NN*256 + b0, ac1);
                        atomicAdd(agg1t + 1*(size_t)NN*256 + b0, ac2);
                        atomicAdd(agg1t + 2*(size_t)NN*256 + b0, ac3);
                    }
                };

                #pragma unroll
                for (int i = 0; i < 8; ++i) {
                    int row = rlo + i;
                    int rn = r_s[cur][row];
                    if (rn != prev_rn) {
                        flush(prev_rn, run_start > rlo);
                        ac0 = ac1 = ac2 = ac3 = 0.f;
                        run_start = row;
                        prev_rn = rn;
                    }
                    float w0 = PKh[row*132 + o];
                    float w1 = PKh[row*132 + 64 + o];
                    float4 y = y_s[cur][row];
                    if (pass == 0) {
                        float x = __uint_as_float(pf[i].x << 16);           // h0
                        ac0 = fmaf(x, w0, ac0);            // A (y0 folded)
                        float xb = x * w1;                 // B
                        ac1 = fmaf(xb, y.y, ac1);
                        ac2 = fmaf(xb, y.z, ac2);
                        ac3 = fmaf(xb, y.w, ac3);
                    } else {
                        float xx = __uint_as_float(pf[i].x & 0xffff0000u);  // h1x
                        float xy = __uint_as_float(pf[i].y << 16);          // h1y
                        float xz = __uint_as_float(pf[i].y & 0xffff0000u);  // h1z
                        float dd = xx*y.y + xy*y.z + xz*y.w;  // D (rs3 in w0)
                        ac0 = fmaf(dd, w0, ac0);
                        ac1 = fmaf(xx, w1, ac1);           // C (y0 in w1)
                        ac2 = fmaf(xy, w1, ac2);
                        ac3 = fmaf(xz, w1, ac3);
                    }
                }
                flush(prev_rn, false);
            }
            lds_barrier();   // PKh reads done before next seg/A1 overwrite
        };

        do_seg(0, 0, pfA);
        do_seg(1, 0, pfA);
        // pfA dead; half-1 prefetch hides under seg(0,1) MFMA
        #pragma unroll
        for (int i = 0; i < 8; ++i)
            pfB[i] = *(const uint2*)(hall + ((size_t)s_s[cur][rlo + i] * 128 + 64 + o) * 4);
        do_seg(0, 1, pfB);
        do_seg(1, 1, pfB);
    }
}

// ---------------- Kernel 3: output transform (MFMA) ----------------
__global__ __launch_bounds__(256) void output_transform(
    const float* __restrict__ agg0,
    const float* __restrict__ agg1t,
    const unsigned short* __restrict__ wp,
    float* __restrict__ out)
{
    __shared__ unsigned short As[4][16 * 264];
    const int t = threadIdx.x;
    const int bn = blockIdx.x * 16;

    for (int i = t; i < 2048; i += 256) {
        int mat = i >> 9;
        int rem = i & 511;
        int n = rem >> 5;
        int ko = (rem & 31) * 8;
        const float* src = (mat == 0)
            ? (agg0 + (size_t)(bn + n) * 256 + ko)
            : (agg1t + (size_t)(mat - 1) * NN * 256 + (size_t)(bn + n) * 256 + ko);
        float4 v0 = *(const float4*)(src);
        float4 v1 = *(const float4*)(src + 4);
        *(short8*)(&As[mat][n * 264 + ko]) = pack8(v0, v1);
    }
    __syncthreads();

    const int wv = t >> 6, lane = t & 63, l16 = lane & 15, l4 = lane >> 4;
    const unsigned short* Wo0p = wp + OFF_WO0;
    const unsigned short* Wo1p = wp + OFF_WO1;

    f32x4 acc[2][4] = {};
    for (int kt = 0; kt < 8; ++kt) {
        short8 a0 = *(const short8*)(&As[0][l16 * 264 + kt * 32 + l4 * 8]);
        short8 a1 = *(const short8*)(&As[1][l16 * 264 + kt * 32 + l4 * 8]);
        short8 a2 = *(const short8*)(&As[2][l16 * 264 + kt * 32 + l4 * 8]);
        short8 a3 = *(const short8*)(&As[3][l16 * 264 + kt * 32 + l4 * 8]);
        #pragma unroll
        for (int n = 0; n < 2; ++n) {
            int col = wv * 32 + n * 16 + l16;
            short8 bw0 = *(const short8*)(Wo0p + ((size_t)kt * 128 + col) * 32 + l4 * 8);
            short8 bw1 = *(const short8*)(Wo1p + ((size_t)kt * 128 + col) * 32 + l4 * 8);
            acc[n][0] = __builtin_amdgcn_mfma_f32_16x16x32_bf16(a0, bw0, acc[n][0], 0, 0, 0);
            acc[n][1] = __builtin_amdgcn_mfma_f32_16x16x32_bf16(a1, bw1, acc[n][1], 0, 0, 0);
            acc[n][2] = __builtin_amdgcn_mfma_f32_16x16x32_bf16(a2, bw1, acc[n][2], 0, 0, 0);
            acc[n][3] = __builtin_amdgcn_mfma_f32_16x16x32_bf16(a3, bw1, acc[n][3], 0, 0, 0);
        }
    }
    const float scale = 0.00390625f; // 1/(sqrt(256)*16)
    #pragma unroll
    for (int n = 0; n < 2; ++n) {
        int col = wv * 32 + n * 16 + l16;
        #pragma unroll
        for (int r = 0; r < 4; ++r) {
            int node = bn + l4 * 4 + r;
            float4 v = make_float4(acc[n][0][r] * scale, acc[n][1][r] * scale,
                                   acc[n][2][r] * scale, acc[n][3][r] * scale);
            *(float4*)(out + ((size_t)node * 128 + col) * 4) = v;
        }
    }
}

extern "C" void kernel_launch(void* const* d_in, const int* in_sizes, int n_in,
                              void* d_out, int out_size, void* d_ws, size_t ws_size,
                              hipStream_t stream) {
    const float* node_feats = (const float*)d_in[0];
    const float* edge_attrs = (const float*)d_in[1];
    const float* edge_feats = (const float*)d_in[2];
    const float* lengths    = (const float*)d_in[3];
    const int*   edge_index = (const int*)d_in[4];
    const float* W_scalar   = (const float*)d_in[5];
    const float* W_up0      = (const float*)d_in[6];
    const float* W_up1      = (const float*)d_in[7];
    const float* W1         = (const float*)d_in[8];
    const float* b1         = (const float*)d_in[9];
    const float* W2         = (const float*)d_in[10];
    const float* b2         = (const float*)d_in[11];
    const float* W3         = (const float*)d_in[12];
    const float* Wout0      = (const float*)d_in[13];
    const float* Wout1      = (const float*)d_in[14];

    float* ws = (float*)d_ws;
    unsigned short* scalars_bf = (unsigned short*)ws;          // [0, 640k) slots
    unsigned short* hall = (unsigned short*)(ws + 640000);     // NN*512 ushort = 2,560,000 slots
    float* agg0  = ws + 3200000;                               // N*256 = 2.56M
    float* agg1t = ws + 5760000;                               // 3*N*256 = 7.68M (ends 13,440,000)
    int* deg    = (int*)(ws + 13440000);                       // 10k
    int* cursor = (int*)(ws + 13450000);                       // 10k
    int* perm   = (int*)(ws + 13460000);                       // 160k
    unsigned short* wpack = (unsigned short*)(ws + 13620000);  // 233472 ushort (ends 13,736,736)
    if (ws_size < 13736736ull * 4ull) return;

    hipMemsetAsync(deg, 0, NN * 4, stream);   // agg zeroing fused into node_transform
    convert_weights<<<(WP_TOTAL + 255) / 256, 256, 0, stream>>>(
        W1, W2, W3, W_scalar, W_up0, W_up1, Wout0, Wout1, wpack, edge_index, deg);
    node_transform<<<625, 256, 0, stream>>>(node_feats, wpack, scalars_bf, hall, agg0, agg1t);
    scan_kernel<<<1, 1024, 0, stream>>>(deg, cursor);
    perm_kernel<<<(NE + 255) / 256, 256, 0, stream>>>(edge_index, cursor, perm);
    edge_kernel<<<NE / TILE / TPB, 256, 0, stream>>>(scalars_bf, hall, edge_attrs, edge_feats, lengths,
                                                     edge_index, perm, b1, b2, wpack, agg0, agg1t);
    output_transform<<<625, 256, 0, stream>>>(agg0, agg1t, wpack, (float*)d_out);
}

// Round 12
// 201.269 us; speedup vs baseline: 1.7662x; 1.7662x over previous
//
#include <hip/hip_runtime.h>
#include <hip/hip_bf16.h>

#define NN 10000
#define NE 160000
#define TILE 32
#define A1S 296   // ushort stride for 288-col staging tile
#define A2S 136   // ushort stride for 128-col tiles

typedef __attribute__((ext_vector_type(8))) short short8;
typedef __attribute__((ext_vector_type(4))) float f32x4;

__device__ __forceinline__ float silu_f(float x) { return x / (1.0f + __expf(-x)); }
__device__ __forceinline__ unsigned short bf16u(float v) {
    __hip_bfloat16 b = __float2bfloat16(v);
    return *reinterpret_cast<unsigned short*>(&b);
}
__device__ __forceinline__ short8 pack8(float4 a, float4 b) {
    short8 r;
    r[0]=(short)bf16u(a.x); r[1]=(short)bf16u(a.y); r[2]=(short)bf16u(a.z); r[3]=(short)bf16u(a.w);
    r[4]=(short)bf16u(b.x); r[5]=(short)bf16u(b.y); r[6]=(short)bf16u(b.z); r[7]=(short)bf16u(b.w);
    return r;
}
// LDS-only barrier: orders DS ops across waves WITHOUT draining vmcnt (atomics stay in flight).
__device__ __forceinline__ void lds_barrier() {
    asm volatile("s_waitcnt lgkmcnt(0)" ::: "memory");
    __builtin_amdgcn_s_barrier();
    asm volatile("" ::: "memory");
}

// packed-weight ushort offsets
#define OFF_W1  0
#define OFF_W2  36864
#define OFF_W3  53248
#define OFF_WSC 118784
#define OFF_WU0 135168
#define OFF_WU1 151552
#define OFF_WO0 167936
#define OFF_WO1 200704
#define WP_TOTAL 233472

// ---------------- Kernel 0: pack weights (+ fused degree histogram) ----------------
__global__ __launch_bounds__(256) void convert_weights(
    const float* __restrict__ W1, const float* __restrict__ W2,
    const float* __restrict__ W3, const float* __restrict__ Wsc,
    const float* __restrict__ Wu0, const float* __restrict__ Wu1,
    const float* __restrict__ Wo0, const float* __restrict__ Wo1,
    unsigned short* __restrict__ wp,
    const int* __restrict__ edge_index, int* __restrict__ deg)
{
    int idx = blockIdx.x * 256 + threadIdx.x;
    if (idx < NE) atomicAdd(&deg[edge_index[NE + idx]], 1);
    if (idx >= WP_TOTAL) return;
    const float* src; int off, N, K;
    if      (idx < OFF_W2)  { src = W1;  off = OFF_W1;  N = 128; K = 265; }
    else if (idx < OFF_W3)  { src = W2;  off = OFF_W2;  N = 128; K = 128; }
    else if (idx < OFF_WSC) { src = W3;  off = OFF_W3;  N = 512; K = 128; }
    else if (idx < OFF_WU0) { src = Wsc; off = OFF_WSC; N = 128; K = 128; }
    else if (idx < OFF_WU1) { src = Wu0; off = OFF_WU0; N = 128; K = 128; }
    else if (idx < OFF_WO0) { src = Wu1; off = OFF_WU1; N = 128; K = 128; }
    else if (idx < OFF_WO1) { src = Wo0; off = OFF_WO0; N = 128; K = 256; }
    else                    { src = Wo1; off = OFF_WO1; N = 128; K = 256; }
    int j = idx - off;
    int kt = j / (N * 32);
    int rem = j % (N * 32);
    int n = rem >> 5, kk = rem & 31;
    int k = kt * 32 + kk;
    wp[idx] = (k < K) ? bf16u(src[k * N + n]) : (unsigned short)0;
}

// ---------------- Kernel 1: node transform (MFMA) + fused agg zeroing ----------------
__global__ __launch_bounds__(256) void node_transform(
    const float* __restrict__ node_feats,
    const unsigned short* __restrict__ wp,
    unsigned short* __restrict__ scalars_bf,
    unsigned short* __restrict__ hall,
    float* __restrict__ agg0, float* __restrict__ agg1t)
{
    __shared__ unsigned short xls[4 * 16 * 136];
    const int t = threadIdx.x;
    const int bn = blockIdx.x * 16;

    // zero this block's agg slices (independent stores; overlap with compute)
    {
        const float4 z = make_float4(0.f, 0.f, 0.f, 0.f);
        float4* a0 = (float4*)(agg0 + (size_t)bn * 256);
        #pragma unroll
        for (int i = 0; i < 4; ++i) a0[t + 256 * i] = z;
        #pragma unroll
        for (int c = 0; c < 3; ++c) {
            float4* a1 = (float4*)(agg1t + (size_t)c * NN * 256 + (size_t)bn * 256);
            #pragma unroll
            for (int i = 0; i < 4; ++i) a1[t + 256 * i] = z;
        }
    }

    for (int i = t; i < 16 * 512; i += 256) {
        int n = i >> 9, j = i & 511;
        unsigned short u = bf16u(node_feats[(size_t)(bn + n) * 512 + j]);
        if (j < 128) xls[n * 136 + j] = u;
        else {
            int jj = j - 128;
            int m = jj / 3;
            int c = jj - 3 * m;
            xls[(1 + c) * 2176 + n * 136 + m] = u;
        }
    }
    __syncthreads();

    const int wv = t >> 6, lane = t & 63, l16 = lane & 15, l4 = lane >> 4;
    const unsigned short* Wscp = wp + OFF_WSC;
    const unsigned short* Wu0p = wp + OFF_WU0;
    const unsigned short* Wu1p = wp + OFF_WU1;

    f32x4 asc[2] = {}, ah0[2] = {}, ah1[3][2] = {};
    for (int kt = 0; kt < 4; ++kt) {
        short8 ax0 = *(const short8*)(xls + l16 * 136 + kt * 32 + l4 * 8);
        short8 ax1[3];
        #pragma unroll
        for (int c = 0; c < 3; ++c)
            ax1[c] = *(const short8*)(xls + (1 + c) * 2176 + l16 * 136 + kt * 32 + l4 * 8);
        #pragma unroll
        for (int n = 0; n < 2; ++n) {
            int col = wv * 32 + n * 16 + l16;
            short8 bsc = *(const short8*)(Wscp + ((size_t)kt * 128 + col) * 32 + l4 * 8);
            short8 bu0 = *(const short8*)(Wu0p + ((size_t)kt * 128 + col) * 32 + l4 * 8);
            short8 bu1 = *(const short8*)(Wu1p + ((size_t)kt * 128 + col) * 32 + l4 * 8);
            asc[n] = __builtin_amdgcn_mfma_f32_16x16x32_bf16(ax0, bsc, asc[n], 0, 0, 0);
            ah0[n] = __builtin_amdgcn_mfma_f32_16x16x32_bf16(ax0, bu0, ah0[n], 0, 0, 0);
            #pragma unroll
            for (int c = 0; c < 3; ++c)
                ah1[c][n] = __builtin_amdgcn_mfma_f32_16x16x32_bf16(ax1[c], bu1, ah1[c][n], 0, 0, 0);
        }
    }
    const float inv = 0.08838834764831845f; // 1/sqrt(128)
    #pragma unroll
    for (int n = 0; n < 2; ++n) {
        int col = wv * 32 + n * 16 + l16;
        #pragma unroll
        for (int r = 0; r < 4; ++r) {
            int node = bn + l4 * 4 + r;
            scalars_bf[(size_t)node * 128 + col] = bf16u(asc[n][r] * inv);
            unsigned int lo = (unsigned int)bf16u(ah0[n][r] * inv)
                            | ((unsigned int)bf16u(ah1[0][n][r] * inv) << 16);
            unsigned int hi = (unsigned int)bf16u(ah1[1][n][r] * inv)
                            | ((unsigned int)bf16u(ah1[2][n][r] * inv) << 16);
            *(uint2*)(hall + ((size_t)node * 128 + col) * 4) = make_uint2(lo, hi);
        }
    }
}

// ---------------- CSR build ----------------
__global__ __launch_bounds__(1024) void scan_kernel(const int* __restrict__ deg,
                                                    int* __restrict__ cursor) {
    __shared__ int s[1024];
    const int t = threadIdx.x;
    const int base = t * 10;
    int ld[10];
    int lsum = 0;
    #pragma unroll
    for (int i = 0; i < 10; ++i) {
        int idx = base + i;
        ld[i] = (idx < NN) ? deg[idx] : 0;
        lsum += ld[i];
    }
    s[t] = lsum;
    __syncthreads();
    for (int off = 1; off < 1024; off <<= 1) {
        int u = (t >= off) ? s[t - off] : 0;
        __syncthreads();
        s[t] += u;
        __syncthreads();
    }
    int run = s[t] - lsum;
    #pragma unroll
    for (int i = 0; i < 10; ++i) {
        int idx = base + i;
        if (idx < NN) cursor[idx] = run;
        run += ld[i];
    }
}

__global__ __launch_bounds__(256) void perm_kernel(const int* __restrict__ edge_index,
                                                   int* __restrict__ cursor,
                                                   int* __restrict__ perm) {
    int e = blockIdx.x * 256 + threadIdx.x;
    if (e < NE) {
        int r = edge_index[NE + e];
        int pos = atomicAdd(&cursor[r], 1);
        perm[pos] = e;
    }
}

// ---------------- Kernel 2: MFMA edge MLP + TP + packed-prefetch run-merged scatter ----------------
// (R10 structure — proven 139.5 µs: single tile per block, fully-inlined segments, no scratch)
__global__ __launch_bounds__(256, 5) void edge_kernel(
    const unsigned short* __restrict__ scalars_bf,
    const unsigned short* __restrict__ hall,
    const float* __restrict__ edge_attrs,
    const float* __restrict__ edge_feats,
    const float* __restrict__ lengths,
    const int* __restrict__ edge_index,
    const int* __restrict__ perm,
    const float* __restrict__ b1, const float* __restrict__ b2,
    const unsigned short* __restrict__ wp,
    float* __restrict__ agg0, float* __restrict__ agg1t)
{
    // LDS: A1 [0,18944) stride A1S; A2 [18944,27648) stride A2S;
    // A3 = A1 region stride A2S -> [0,8704); PKh fp32 [32][132] at [8704,25600).
    __shared__ unsigned char smem_u[27648];
    __shared__ int   eid_s[TILE];
    __shared__ int   s_s[TILE];
    __shared__ int   r_s[TILE];
    __shared__ float4 y_s[TILE];

    unsigned short* A1 = (unsigned short*)smem_u;
    unsigned short* A2 = (unsigned short*)(smem_u + 18944);
    unsigned short* A3 = A1;
    float* PKh = (float*)(smem_u + 8704);

    const int t = threadIdx.x;
    const int e0 = blockIdx.x * TILE;
    const int wv = t >> 6;
    const int lane = t & 63;
    const int l16 = lane & 15;
    const int l4 = lane >> 4;

    if (t < TILE) {
        int eid = perm[e0 + t];
        eid_s[t] = eid;
        s_s[t] = edge_index[eid];
        r_s[t] = edge_index[NE + eid];
        y_s[t] = *(const float4*)(edge_attrs + (size_t)eid * 4);
    }
    __syncthreads();

    // ---- stage mlp_in (bf16) into A1 (VMEM loads issued first: vmcnt FIFO) ----
    {
        const int e = t >> 3, j = t & 7;
        const unsigned short* srow = scalars_bf + (size_t)s_s[e] * 128;
        const unsigned short* rrow = scalars_bf + (size_t)r_s[e] * 128;
        *(uint4*)(A1 + e*A1S + j*16)       = *(const uint4*)(srow + j*16);
        *(uint4*)(A1 + e*A1S + j*16 + 8)   = *(const uint4*)(srow + j*16 + 8);
        *(uint4*)(A1 + e*A1S + 128 + j*16)     = *(const uint4*)(rrow + j*16);
        *(uint4*)(A1 + e*A1S + 128 + j*16 + 8) = *(const uint4*)(rrow + j*16 + 8);
        A1[e*A1S + 256 + j] = bf16u(edge_feats[(size_t)eid_s[e] * 8 + j]);
        if (t < TILE) A1[t*A1S + 264] = bf16u(lengths[eid_s[t]]);
        for (int i = t; i < TILE * 23; i += 256) {
            int row = i / 23, c = 265 + (i - row * 23);
            A1[row*A1S + c] = 0;
        }
    }

    // ---- prefetch packed gather operands for cols o (half 0): 8 x 8B = 16 VGPR ----
    const int q = t >> 6, o = t & 63;   // scatter role: wave q owns rows [q*8, q*8+8), col o
    const int rlo = q * 8;
    uint2 pfA[8], pfB[8];
    #pragma unroll
    for (int i = 0; i < 8; ++i)
        pfA[i] = *(const uint2*)(hall + ((size_t)s_s[rlo + i] * 128 + o) * 4);
    __syncthreads();

    const unsigned short* Wp1 = wp + OFF_W1;
    const unsigned short* Wp2 = wp + OFF_W2;
    const unsigned short* Wp3 = wp + OFF_W3;

    // ---- layer 1: (32 x 288) @ (288 x 128) ----
    {
        f32x4 acc[2][2] = {};
        for (int kt = 0; kt < 9; ++kt) {
            short8 a0 = *(const short8*)(A1 + (     l16)*A1S + kt*32 + l4*8);
            short8 a1 = *(const short8*)(A1 + (16 + l16)*A1S + kt*32 + l4*8);
            #pragma unroll
            for (int n = 0; n < 2; ++n) {
                int col = (2*wv + n)*16 + l16;
                short8 b = *(const short8*)(Wp1 + ((size_t)kt*128 + col)*32 + l4*8);
                acc[0][n] = __builtin_amdgcn_mfma_f32_16x16x32_bf16(a0, b, acc[0][n], 0, 0, 0);
                acc[1][n] = __builtin_amdgcn_mfma_f32_16x16x32_bf16(a1, b, acc[1][n], 0, 0, 0);
            }
        }
        #pragma unroll
        for (int n = 0; n < 2; ++n) {
            int col = (2*wv + n)*16 + l16;
            float bb = b1[col];
            #pragma unroll
            for (int m = 0; m < 2; ++m)
                #pragma unroll
                for (int r = 0; r < 4; ++r) {
                    int row = m*16 + l4*4 + r;
                    A2[row*A2S + col] = bf16u(silu_f(acc[m][n][r] + bb));
                }
        }
    }
    __syncthreads();

    // ---- layer 2: (32 x 128) @ (128 x 128) -> A3 ----
    {
        f32x4 acc[2][2] = {};
        for (int kt = 0; kt < 4; ++kt) {
            short8 a0 = *(const short8*)(A2 + (     l16)*A2S + kt*32 + l4*8);
            short8 a1 = *(const short8*)(A2 + (16 + l16)*A2S + kt*32 + l4*8);
            #pragma unroll
            for (int n = 0; n < 2; ++n) {
                int col = (2*wv + n)*16 + l16;
                short8 b = *(const short8*)(Wp2 + ((size_t)kt*128 + col)*32 + l4*8);
                acc[0][n] = __builtin_amdgcn_mfma_f32_16x16x32_bf16(a0, b, acc[0][n], 0, 0, 0);
                acc[1][n] = __builtin_amdgcn_mfma_f32_16x16x32_bf16(a1, b, acc[1][n], 0, 0, 0);
            }
        }
        #pragma unroll
        for (int n = 0; n < 2; ++n) {
            int col = (2*wv + n)*16 + l16;
            float bb = b2[col];
            #pragma unroll
            for (int m = 0; m < 2; ++m)
                #pragma unroll
                for (int r = 0; r < 4; ++r) {
                    int row = m*16 + l4*4 + r;
                    A3[row*A2S + col] = bf16u(silu_f(acc[m][n][r] + bb));
                }
        }
    }
    __syncthreads();   // A3 visible; PKh region (dead A1-tail/A2) usable

    // ---- layer 3: 4 segments {pass, half}; PKh handoff uses LDS-only barriers so the
    //      scatter atomics are NEVER drained mid-kernel (no vmcnt(0) until endpgm). ----
    const float rs3 = 0.57735026918962576f;
    auto do_seg = [&](const int pass, const int hh, const uint2* pf) {
        const int base0 = pass ? 128 : 0;
        const int base1 = pass ? 384 : 256;
        f32x4 acc[2][2] = {};   // [fam][m]
        for (int kt = 0; kt < 4; ++kt) {
            short8 a0 = *(const short8*)(A3 + (     l16)*A2S + kt*32 + l4*8);
            short8 a1 = *(const short8*)(A3 + (16 + l16)*A2S + kt*32 + l4*8);
            #pragma unroll
            for (int fam = 0; fam < 2; ++fam) {
                int col = (fam ? base1 : base0) + hh*64 + wv*16 + l16;
                short8 b = *(const short8*)(Wp3 + ((size_t)kt*512 + col)*32 + l4*8);
                acc[fam][0] = __builtin_amdgcn_mfma_f32_16x16x32_bf16(a0, b, acc[fam][0], 0, 0, 0);
                acc[fam][1] = __builtin_amdgcn_mfma_f32_16x16x32_bf16(a1, b, acc[fam][1], 0, 0, 0);
            }
        }
        #pragma unroll
        for (int fam = 0; fam < 2; ++fam)
            #pragma unroll
            for (int m = 0; m < 2; ++m)
                #pragma unroll
                for (int r = 0; r < 4; ++r) {
                    int row = m*16 + l4*4 + r;
                    float y0 = y_s[row].x;
                    float fold = (fam == 0) ? (pass ? rs3 : y0) : (pass ? y0 : 1.0f);
                    PKh[row*132 + fam*64 + wv*16 + l16] = acc[fam][m][r] * fold;
                }
        lds_barrier();   // PKh visible to all waves; atomics from prior segs stay in flight

        // scatter: thread t -> col (hh*64+o), rows rlo..rlo+7; operands unpacked from pf
        {
            const int ocol = hh*64 + o;
            float ac0 = 0.f, ac1 = 0.f, ac2 = 0.f, ac3 = 0.f;
            int run_start = rlo;
            int prev_rn = r_s[rlo];

            auto flush = [&](int rn, bool interior) {
                size_t b0 = (size_t)rn * 256 + base0 + ocol;
                if (interior) {
                    agg0[b0] = ac0;
                    agg1t[0*(size_t)NN*256 + b0] = ac1;
                    agg1t[1*(size_t)NN*256 + b0] = ac2;
                    agg1t[2*(size_t)NN*256 + b0] = ac3;
                } else {
                    atomicAdd(agg0 + b0, ac0);
                    atomicAdd(agg1t + 0*(size_t)NN*256 + b0, ac1);
                    atomicAdd(agg1t + 1*(size_t)NN*256 + b0, ac2);
                    atomicAdd(agg1t + 2*(size_t)NN*256 + b0, ac3);
                }
            };

            #pragma unroll
            for (int i = 0; i < 8; ++i) {
                int row = rlo + i;
                int rn = r_s[row];
                if (rn != prev_rn) {
                    flush(prev_rn, run_start > rlo);
                    ac0 = ac1 = ac2 = ac3 = 0.f;
                    run_start = row;
                    prev_rn = rn;
                }
                float w0 = PKh[row*132 + o];
                float w1 = PKh[row*132 + 64 + o];
                float4 y = y_s[row];
                if (pass == 0) {
                    float x = __uint_as_float(pf[i].x << 16);           // h0
                    ac0 = fmaf(x, w0, ac0);            // A (y0 folded)
                    float xb = x * w1;                 // B
                    ac1 = fmaf(xb, y.y, ac1);
                    ac2 = fmaf(xb, y.z, ac2);
                    ac3 = fmaf(xb, y.w, ac3);
                } else {
                    float xx = __uint_as_float(pf[i].x & 0xffff0000u);  // h1x
                    float xy = __uint_as_float(pf[i].y << 16);          // h1y
                    float xz = __uint_as_float(pf[i].y & 0xffff0000u);  // h1z
                    float dd = xx*y.y + xy*y.z + xz*y.w;  // D (rs3 folded into w0)
                    ac0 = fmaf(dd, w0, ac0);
                    ac1 = fmaf(xx, w1, ac1);           // C (y0 folded into w1)
                    ac2 = fmaf(xy, w1, ac2);
                    ac3 = fmaf(xz, w1, ac3);
                }
            }
            flush(prev_rn, false);
        }
        lds_barrier();   // all PKh reads done before next seg overwrites (no atomic drain)
    };

    do_seg(0, 0, pfA);
    do_seg(1, 0, pfA);
    // pfA dead; issue half-1 prefetch — latency hides under seg(0,1)'s MFMA phase
    #pragma unroll
    for (int i = 0; i < 8; ++i)
        pfB[i] = *(const uint2*)(hall + ((size_t)s_s[rlo + i] * 128 + 64 + o) * 4);
    do_seg(0, 1, pfB);
    do_seg(1, 1, pfB);
}

// ---------------- Kernel 3: output transform (MFMA) ----------------
__global__ __launch_bounds__(256) void output_transform(
    const float* __restrict__ agg0,
    const float* __restrict__ agg1t,
    const unsigned short* __restrict__ wp,
    float* __restrict__ out)
{
    __shared__ unsigned short As[4][16 * 264];
    const int t = threadIdx.x;
    const int bn = blockIdx.x * 16;

    for (int i = t; i < 2048; i += 256) {
        int mat = i >> 9;
        int rem = i & 511;
        int n = rem >> 5;
        int ko = (rem & 31) * 8;
        const float* src = (mat == 0)
            ? (agg0 + (size_t)(bn + n) * 256 + ko)
            : (agg1t + (size_t)(mat - 1) * NN * 256 + (size_t)(bn + n) * 256 + ko);
        float4 v0 = *(const float4*)(src);
        float4 v1 = *(const float4*)(src + 4);
        *(short8*)(&As[mat][n * 264 + ko]) = pack8(v0, v1);
    }
    __syncthreads();

    const int wv = t >> 6, lane = t & 63, l16 = lane & 15, l4 = lane >> 4;
    const unsigned short* Wo0p = wp + OFF_WO0;
    const unsigned short* Wo1p = wp + OFF_WO1;

    f32x4 acc[2][4] = {};
    for (int kt = 0; kt < 8; ++kt) {
        short8 a0 = *(const short8*)(&As[0][l16 * 264 + kt * 32 + l4 * 8]);
        short8 a1 = *(const short8*)(&As[1][l16 * 264 + kt * 32 + l4 * 8]);
        short8 a2 = *(const short8*)(&As[2][l16 * 264 + kt * 32 + l4 * 8]);
        short8 a3 = *(const short8*)(&As[3][l16 * 264 + kt * 32 + l4 * 8]);
        #pragma unroll
        for (int n = 0; n < 2; ++n) {
            int col = wv * 32 + n * 16 + l16;
            short8 bw0 = *(const short8*)(Wo0p + ((size_t)kt * 128 + col) * 32 + l4 * 8);
            short8 bw1 = *(const short8*)(Wo1p + ((size_t)kt * 128 + col) * 32 + l4 * 8);
            acc[n][0] = __builtin_amdgcn_mfma_f32_16x16x32_bf16(a0, bw0, acc[n][0], 0, 0, 0);
            acc[n][1] = __builtin_amdgcn_mfma_f32_16x16x32_bf16(a1, bw1, acc[n][1], 0, 0, 0);
            acc[n][2] = __builtin_amdgcn_mfma_f32_16x16x32_bf16(a2, bw1, acc[n][2], 0, 0, 0);
            acc[n][3] = __builtin_amdgcn_mfma_f32_16x16x32_bf16(a3, bw1, acc[n][3], 0, 0, 0);
        }
    }
    const float scale = 0.00390625f; // 1/(sqrt(256)*16)
    #pragma unroll
    for (int n = 0; n < 2; ++n) {
        int col = wv * 32 + n * 16 + l16;
        #pragma unroll
        for (int r = 0; r < 4; ++r) {
            int node = bn + l4 * 4 + r;
            float4 v = make_float4(acc[n][0][r] * scale, acc[n][1][r] * scale,
                                   acc[n][2][r] * scale, acc[n][3][r] * scale);
            *(float4*)(out + ((size_t)node * 128 + col) * 4) = v;
        }
    }
}

extern "C" void kernel_launch(void* const* d_in, const int* in_sizes, int n_in,
                              void* d_out, int out_size, void* d_ws, size_t ws_size,
                              hipStream_t stream) {
    const float* node_feats = (const float*)d_in[0];
    const float* edge_attrs = (const float*)d_in[1];
    const float* edge_feats = (const float*)d_in[2];
    const float* lengths    = (const float*)d_in[3];
    const int*   edge_index = (const int*)d_in[4];
    const float* W_scalar   = (const float*)d_in[5];
    const float* W_up0      = (const float*)d_in[6];
    const float* W_up1      = (const float*)d_in[7];
    const float* W1         = (const float*)d_in[8];
    const float* b1         = (const float*)d_in[9];
    const float* W2         = (const float*)d_in[10];
    const float* b2         = (const float*)d_in[11];
    const float* W3         = (const float*)d_in[12];
    const float* Wout0      = (const float*)d_in[13];
    const float* Wout1      = (const float*)d_in[14];

    float* ws = (float*)d_ws;
    unsigned short* scalars_bf = (unsigned short*)ws;          // [0, 640k) slots
    unsigned short* hall = (unsigned short*)(ws + 640000);     // NN*512 ushort = 2,560,000 slots
    float* agg0  = ws + 3200000;                               // N*256 = 2.56M
    float* agg1t = ws + 5760000;                               // 3*N*256 = 7.68M (ends 13,440,000)
    int* deg    = (int*)(ws + 13440000);                       // 10k
    int* cursor = (int*)(ws + 13450000);                       // 10k
    int* perm   = (int*)(ws + 13460000);                       // 160k
    unsigned short* wpack = (unsigned short*)(ws + 13620000);  // 233472 ushort (ends 13,736,736)
    if (ws_size < 13736736ull * 4ull) return;

    hipMemsetAsync(deg, 0, NN * 4, stream);   // agg zeroing fused into node_transform
    convert_weights<<<(WP_TOTAL + 255) / 256, 256, 0, stream>>>(
        W1, W2, W3, W_scalar, W_up0, W_up1, Wout0, Wout1, wpack, edge_index, deg);
    node_transform<<<625, 256, 0, stream>>>(node_feats, wpack, scalars_bf, hall, agg0, agg1t);
    scan_kernel<<<1, 1024, 0, stream>>>(deg, cursor);
    perm_kernel<<<(NE + 255) / 256, 256, 0, stream>>>(edge_index, cursor, perm);
    edge_kernel<<<NE / TILE, 256, 0, stream>>>(scalars_bf, hall, edge_attrs, edge_feats, lengths,
                                               edge_index, perm, b1, b2, wpack, agg0, agg1t);
    output_transform<<<625, 256, 0, stream>>>(agg0, agg1t, wpack, (float*)d_out);
}